// Round 5
// baseline (515.739 us; speedup 1.0000x reference)
//
#include <hip/hip_runtime.h>
#include <hip/hip_bf16.h>

// Sizes fixed by the reference problem.
#define CN 32
#define RN 256
#define DN 512
#define NN 32
#define LN 256

// LDS layout of main kernel (bytes):
//  sAt : bf16 [256][256] = 131072, 16B-chunk XOR swizzle (chunk ^= r&7)
//  epilogue reductions overlaid after sAt: w12s 8K + nsqS 1K + red 32B
#define RED_BASE 131072
#define SMEM_TOTAL (131072 + 9216 + 64)

typedef short v8s __attribute__((ext_vector_type(8)));
typedef float v4f __attribute__((ext_vector_type(4)));

__device__ __forceinline__ unsigned short f2bf(float x) {
  unsigned int u = __float_as_uint(x);
  u = (u + 0x7fffu + ((u >> 16) & 1u)) >> 16;  // RNE
  return (unsigned short)u;
}
__device__ __forceinline__ float bf2f(unsigned short h) {
  return __uint_as_float(((unsigned int)h) << 16);
}

// sAt addressing: row-major stride 256 shorts, 16B chunks XOR-swizzled by row.
__device__ __forceinline__ int satIdx(int r, int col) {
  return (r << 8) | ((((col >> 3) ^ (r & 7)) << 3) | (col & 7));
}

// ---------------------------------------------------------------------------
// Prep: fp32 -> bf16 copies of laws & contracts, plus ||contracts[c,r,:]||.
// Fully vectorized: float4 loads, ushort8 (16B) stores.
// blocks 0..2047: contracts (4 rows each, with row norms);
// blocks 2048..4095: laws (2048 elements each; laws = 4,194,304 floats total).
// ---------------------------------------------------------------------------
__global__ __launch_bounds__(256) void prep_kernel(
    const float* __restrict__ con, const float* __restrict__ laws,
    unsigned short* __restrict__ lawsB, unsigned short* __restrict__ conB,
    float* __restrict__ cnorm) {
  const int bid = blockIdx.x;
  const int t = threadIdx.x;
  if (bid < 2048) {
    const int r = bid * 4 + (t >> 6);
    const int lane = t & 63;
    const float4* src = (const float4*)(con + r * DN + lane * 8);
    float4 x0 = src[0], x1 = src[1];
    unsigned short h[8];
    h[0] = f2bf(x0.x); h[1] = f2bf(x0.y); h[2] = f2bf(x0.z); h[3] = f2bf(x0.w);
    h[4] = f2bf(x1.x); h[5] = f2bf(x1.y); h[6] = f2bf(x1.z); h[7] = f2bf(x1.w);
    *(v8s*)(conB + r * DN + lane * 8) = *(v8s*)h;
    float s = x0.x * x0.x + x0.y * x0.y + x0.z * x0.z + x0.w * x0.w +
              x1.x * x1.x + x1.y * x1.y + x1.z * x1.z + x1.w * x1.w;
#pragma unroll
    for (int m = 1; m < 64; m <<= 1) s += __shfl_xor(s, m, 64);
    if (lane == 0) cnorm[r] = sqrtf(s);
  } else {
    const int off = (bid - 2048) * 2048 + t * 8;
    const float4* src = (const float4*)(laws + off);
    float4 x0 = src[0], x1 = src[1];
    unsigned short h[8];
    h[0] = f2bf(x0.x); h[1] = f2bf(x0.y); h[2] = f2bf(x0.z); h[3] = f2bf(x0.w);
    h[4] = f2bf(x1.x); h[5] = f2bf(x1.y); h[6] = f2bf(x1.z); h[7] = f2bf(x1.w);
    *(v8s*)(lawsB + off) = *(v8s*)h;
  }
}

// ---------------------------------------------------------------------------
// Gram via MFMA, direct-global fragments, no LDS, no barriers.
// 128 blocks = (n, 64-row quarter). Wave tile: 32 rows x 64 cols.
// ---------------------------------------------------------------------------
__global__ __launch_bounds__(512) void gramm_kernel(
    const unsigned short* __restrict__ lawsB, unsigned short* __restrict__ G) {
  const int bx = blockIdx.x;
  const int n = bx >> 2;
  const int m0 = (bx & 3) << 6;
  const int t = threadIdx.x;
  const int lane = t & 63;
  const int w = t >> 6;
  const int quad = lane >> 4;
  const int l16 = lane & 15;
  const unsigned short* lawN = lawsB + n * (LN * DN);
  const int wr = (w & 1) << 5;   // wave row offset (local in 64)
  const int wc = (w >> 1) << 6;  // wave col offset

  const unsigned short* a0p = lawN + (m0 + wr + l16) * DN + quad * 8;
  const unsigned short* a1p = a0p + 16 * DN;
  const unsigned short* bp = lawN + (wc + l16) * DN + quad * 8;

  v4f acc[2][4];
#pragma unroll
  for (int a = 0; a < 2; ++a)
#pragma unroll
    for (int b = 0; b < 4; ++b) acc[a][b] = (v4f){0.f, 0.f, 0.f, 0.f};

#pragma unroll 2
  for (int ch = 0; ch < 16; ++ch) {
    const int dk = ch << 5;
    v8s af0 = *(const v8s*)(a0p + dk);
    v8s af1 = *(const v8s*)(a1p + dk);
    v8s bfr[4];
#pragma unroll
    for (int rt = 0; rt < 4; ++rt)
      bfr[rt] = *(const v8s*)(bp + rt * (16 * DN) + dk);
#pragma unroll
    for (int rt = 0; rt < 4; ++rt) {
      acc[0][rt] = __builtin_amdgcn_mfma_f32_16x16x32_bf16(af0, bfr[rt], acc[0][rt], 0, 0, 0);
      acc[1][rt] = __builtin_amdgcn_mfma_f32_16x16x32_bf16(af1, bfr[rt], acc[1][rt], 0, 0, 0);
    }
  }
  unsigned short* g = G + n * (LN * LN);
#pragma unroll
  for (int tl = 0; tl < 2; ++tl)
#pragma unroll
    for (int reg = 0; reg < 4; ++reg) {
      const int l = m0 + wr + tl * 16 + quad * 4 + reg;
#pragma unroll
      for (int rt = 0; rt < 4; ++rt)
        g[l * LN + wc + rt * 16 + l16] = f2bf(acc[tl][rt][reg]);
    }
}

// ---------------------------------------------------------------------------
// Main: one block per (n,c), 512 threads (8 waves). Fragments loaded DIRECTLY
// from global (16B/lane) -> no LDS staging, no K-loop barriers.
// Phase A: S = laws[n]@con[c]^T, softmax rows in-reg, attn^T -> sAt (LDS),
//          w12 partials in registers.
// Phase B: U = At@G (G via direct global frags); nsq[r] = sum_l At[r,l]U[r,l].
// Phase C: sim = sqrt(D)*w12/(w1*w2); out[c,n] = LSE_6 over r.
// ---------------------------------------------------------------------------
__global__ __launch_bounds__(512, 2) void main_kernel(
    const int* __restrict__ law_lens, const unsigned short* __restrict__ lawsB,
    const unsigned short* __restrict__ conB, const unsigned short* __restrict__ Gm,
    const float* __restrict__ cnorm, float* __restrict__ out) {
  extern __shared__ char smem[];
  unsigned short* sAt = (unsigned short*)smem;  // [256][256] swizzled

  const int bid = blockIdx.x;
  const int n = bid >> 5;  // 32 consecutive blocks share one n
  const int c = bid & 31;
  const int t = threadIdx.x;
  const int lane = t & 63;
  const int w = t >> 6;  // wave 0..7
  const int quad = lane >> 4;
  const int l16 = lane & 15;
  const int len = law_lens[n];

  const unsigned short* lawN = lawsB + n * (LN * DN);
  const unsigned short* conC = conB + c * (RN * DN);
  const unsigned short* Gn = Gm + n * (LN * LN);

  float w12p[16];
#pragma unroll
  for (int i = 0; i < 16; ++i) w12p[i] = 0.f;

  // ---------------- Phase A ----------------
  {
    const unsigned short* a0p = lawN + (w * 32 + l16) * DN + quad * 8;
    const unsigned short* a1p = a0p + 16 * DN;
    const unsigned short* bp = conC + l16 * DN + quad * 8;

    v4f acc[2][16];
#pragma unroll
    for (int a = 0; a < 2; ++a)
#pragma unroll
      for (int b = 0; b < 16; ++b) acc[a][b] = (v4f){0.f, 0.f, 0.f, 0.f};

#pragma unroll 2
    for (int ch = 0; ch < 16; ++ch) {
      const int dk = ch << 5;
      v8s af0 = *(const v8s*)(a0p + dk);
      v8s af1 = *(const v8s*)(a1p + dk);
      v8s bfr[16];
#pragma unroll
      for (int rt = 0; rt < 16; ++rt)
        bfr[rt] = *(const v8s*)(bp + rt * (16 * DN) + dk);
#pragma unroll
      for (int rt = 0; rt < 16; ++rt) {
        acc[0][rt] = __builtin_amdgcn_mfma_f32_16x16x32_bf16(af0, bfr[rt], acc[0][rt], 0, 0, 0);
        acc[1][rt] = __builtin_amdgcn_mfma_f32_16x16x32_bf16(af1, bfr[rt], acc[1][rt], 0, 0, 0);
      }
    }
    // Row ops: row l lives in 16 lanes (C layout col=lane&15 -> r index).
    // 4 regs of a tile = 4 consecutive sAt columns -> packed b64 writes.
#pragma unroll
    for (int tl = 0; tl < 2; ++tl) {
      unsigned int pk[16][2];
#pragma unroll
      for (int reg = 0; reg < 4; ++reg) {
        const int lg = w * 32 + tl * 16 + quad * 4 + reg;
        float v[16], lv[16];
        float ss = 0.f, mx = -1e30f;
#pragma unroll
        for (int rt = 0; rt < 16; ++rt) {
          v[rt] = acc[tl][rt][reg] * 0.04419417382415922f;  // 1/sqrt(512)
          lv[rt] = v[rt] > 0.f ? v[rt] : 0.1f * v[rt];
          ss += lv[rt] * lv[rt];
          mx = fmaxf(mx, lv[rt]);
        }
#pragma unroll
        for (int m = 1; m < 16; m <<= 1) {
          ss += __shfl_xor(ss, m, 64);
          mx = fmaxf(mx, __shfl_xor(mx, m, 64));
        }
        const float inv = 1.f / (sqrtf(ss) + 1e-8f);
        const float xm = mx * inv;
        float e[16];
        float den = 0.f;
#pragma unroll
        for (int rt = 0; rt < 16; ++rt) {
          e[rt] = __expf(lv[rt] * inv - xm);
          den += e[rt];
        }
#pragma unroll
        for (int m = 1; m < 16; m <<= 1) den += __shfl_xor(den, m, 64);
        const float sc = (lg < len) ? 4.f / den : 0.f;  // SMOOTH/denom, masked
#pragma unroll
        for (int rt = 0; rt < 16; ++rt) {
          const float a = e[rt] * sc;
          w12p[rt] += a * v[rt];  // raw S -> cosine numerator
          const unsigned int h = f2bf(a);
          if (reg & 1)
            pk[rt][reg >> 1] |= h << 16;
          else
            pk[rt][reg >> 1] = h;
        }
      }
      const int lg0 = w * 32 + tl * 16 + quad * 4;
#pragma unroll
      for (int rt = 0; rt < 16; ++rt)
        *(uint2*)(sAt + satIdx(rt * 16 + l16, lg0)) = *(uint2*)pk[rt];
    }
  }
  // Reduce w12 partials across quads; keep in registers through phase B.
#pragma unroll
  for (int rt = 0; rt < 16; ++rt) {
    w12p[rt] += __shfl_xor(w12p[rt], 16, 64);
    w12p[rt] += __shfl_xor(w12p[rt], 32, 64);
  }

  __syncthreads();  // sAt writes (all waves) -> phase B reads

  // ---------------- Phase B ----------------
  float nsv[2][4];
  {
    const unsigned short* gp = Gn + l16 * LN + quad * 8;
    v4f acc[2][16];
#pragma unroll
    for (int a = 0; a < 2; ++a)
#pragma unroll
      for (int b = 0; b < 16; ++b) acc[a][b] = (v4f){0.f, 0.f, 0.f, 0.f};

#pragma unroll 2
    for (int ch = 0; ch < 8; ++ch) {
      const int lk = ch << 5;
      v8s af0 = *(const v8s*)(sAt + satIdx(w * 32 + l16, lk + quad * 8));
      v8s af1 = *(const v8s*)(sAt + satIdx(w * 32 + 16 + l16, lk + quad * 8));
      v8s bfr[16];
#pragma unroll
      for (int lt = 0; lt < 16; ++lt)
        bfr[lt] = *(const v8s*)(gp + lt * (16 * LN) + lk);  // G row (symmetric)
#pragma unroll
      for (int lt = 0; lt < 16; ++lt) {
        acc[0][lt] = __builtin_amdgcn_mfma_f32_16x16x32_bf16(af0, bfr[lt], acc[0][lt], 0, 0, 0);
        acc[1][lt] = __builtin_amdgcn_mfma_f32_16x16x32_bf16(af1, bfr[lt], acc[1][lt], 0, 0, 0);
      }
    }
    // nsq[r] = sum_l At[r,l] * U[r,l] (reads sAt + registers only)
#pragma unroll
    for (int tl = 0; tl < 2; ++tl) {
#pragma unroll
      for (int reg = 0; reg < 4; ++reg) {
        const int r = w * 32 + tl * 16 + quad * 4 + reg;
        float s = 0.f;
#pragma unroll
        for (int lt = 0; lt < 16; ++lt)
          s += acc[tl][lt][reg] * bf2f(sAt[satIdx(r, lt * 16 + l16)]);
#pragma unroll
        for (int m = 1; m < 16; m <<= 1) s += __shfl_xor(s, m, 64);
        nsv[tl][reg] = s;
      }
    }
  }

  // ---------------- Phase C ----------------
  float* w12s = (float*)(smem + RED_BASE);         // [8][256]
  float* nsqS = (float*)(smem + RED_BASE + 8192);  // [256]
  float* red = (float*)(smem + RED_BASE + 9216);   // [8]
  if (l16 == 0) {
#pragma unroll
    for (int tl = 0; tl < 2; ++tl)
#pragma unroll
      for (int reg = 0; reg < 4; ++reg)
        nsqS[w * 32 + tl * 16 + quad * 4 + reg] = nsv[tl][reg];
  }
  if (lane < 16) {
#pragma unroll
    for (int rt = 0; rt < 16; ++rt) w12s[w * 256 + rt * 16 + lane] = w12p[rt];
  }
  __syncthreads();
  float p = 0.f;
  if (t < 256) {
    float w12 = 0.f;
#pragma unroll
    for (int i = 0; i < 8; ++i) w12 += w12s[i * 256 + t];
    const float w1 = cnorm[c * RN + t];
    const float w2 = sqrtf(fmaxf(nsqS[t], 0.f));
    const float sim = (w12 * 22.627416997969522f) / fmaxf(w1 * w2, 1e-8f);
    p = __expf(6.f * sim);
  }
#pragma unroll
  for (int m = 1; m < 64; m <<= 1) p += __shfl_xor(p, m, 64);
  if (lane == 0) red[w] = p;
  __syncthreads();
  if (t == 0) {
    float s = 0.f;
#pragma unroll
    for (int i = 0; i < 8; ++i) s += red[i];
    out[c * NN + n] = logf(s) / 6.f;
  }
}

// ---------------------------------------------------------------------------
extern "C" void kernel_launch(void* const* d_in, const int* in_sizes, int n_in,
                              void* d_out, int out_size, void* d_ws, size_t ws_size,
                              hipStream_t stream) {
  (void)in_sizes; (void)n_in; (void)out_size;
  const float* contracts = (const float*)d_in[0];
  const float* laws = (const float*)d_in[1];
  const int* law_lens = (const int*)d_in[2];
  float* out = (float*)d_out;

  // Workspace layout (21,004,288 B total)
  unsigned short* lawsB = (unsigned short*)d_ws;  // 8 MiB
  unsigned short* conB = lawsB + NN * LN * DN;    // 8 MiB
  unsigned short* G = conB + CN * RN * DN;        // 4 MiB
  float* cnorm = (float*)(G + NN * LN * LN);      // 32 KiB
  if (ws_size < (size_t)21004288) return;

  hipFuncSetAttribute((const void*)main_kernel,
                      hipFuncAttributeMaxDynamicSharedMemorySize, SMEM_TOTAL);

  // 2048 contract blocks + 2048 laws blocks (laws = 4,194,304 floats / 2048).
  prep_kernel<<<4096, 256, 0, stream>>>(contracts, laws, lawsB, conB, cnorm);
  gramm_kernel<<<128, 512, 0, stream>>>(lawsB, G);
  main_kernel<<<1024, 512, SMEM_TOTAL, stream>>>(law_lens, lawsB, conB, G, cnorm, out);
}

// Round 6
// 322.371 us; speedup vs baseline: 1.5998x; 1.5998x over previous
//
#include <hip/hip_runtime.h>
#include <hip/hip_bf16.h>

// Sizes fixed by the reference problem.
#define CN 32
#define RN 256
#define DN 512
#define NN 32
#define LN 256

// LDS layout of main kernel (bytes):
//  sAt   : bf16 [256][256] = 131072, 16B-chunk XOR swizzle (chunk ^= r&7)
//  stage : 32768 = double-buffered staging (conS / Gs), 16K per buffer.
//          Epilogue reductions (w12s 8K, nsqS 1K, red) overlay this region.
//  total : 163840 = exactly 160 KiB (1 block/CU, 8 waves)
#define STAGE_OFF 131072
#define SMEM_TOTAL 163840

typedef short v8s __attribute__((ext_vector_type(8)));
typedef float v4f __attribute__((ext_vector_type(4)));
typedef const __attribute__((address_space(1))) void* gas1_t;
typedef __attribute__((address_space(3))) void* las3_t;

__device__ __forceinline__ void gl2lds16(const void* g, void* l) {
  __builtin_amdgcn_global_load_lds((gas1_t)g, (las3_t)l, 16, 0, 0);
}

__device__ __forceinline__ unsigned short f2bf(float x) {
  unsigned int u = __float_as_uint(x);
  u = (u + 0x7fffu + ((u >> 16) & 1u)) >> 16;  // RNE
  return (unsigned short)u;
}
__device__ __forceinline__ float bf2f(unsigned short h) {
  return __uint_as_float(((unsigned int)h) << 16);
}

// Staging buffers ([256][32] shorts): 16B chunks XOR-swizzled with (r>>1)&3.
// Writes absorb the swizzle in the global fetch column; reads via this helper.
// 2-way bank aliasing only (free, m136).
__device__ __forceinline__ const v8s* stgFrag(const unsigned short* buf, int r,
                                              int quad) {
  return (const v8s*)(buf + r * 32 + ((quad ^ ((r >> 1) & 3)) << 3));
}

// sAt addressing: row-major stride 256 shorts, 16B chunks XOR-swizzled by row.
__device__ __forceinline__ int satIdx(int r, int col) {
  return (r << 8) | ((((col >> 3) ^ (r & 7)) << 3) | (col & 7));
}

// Load 8 consecutive fp32 and convert to bf16x8 fragment.
__device__ __forceinline__ v8s ld8f(const float* p) {
  const float4* s = (const float4*)p;
  float4 x0 = s[0], x1 = s[1];
  unsigned short h[8];
  h[0] = f2bf(x0.x); h[1] = f2bf(x0.y); h[2] = f2bf(x0.z); h[3] = f2bf(x0.w);
  h[4] = f2bf(x1.x); h[5] = f2bf(x1.y); h[6] = f2bf(x1.z); h[7] = f2bf(x1.w);
  return *(v8s*)h;
}

// ---------------------------------------------------------------------------
// Fused prep + gram (independent works, one launch):
//  blocks 0..2047   : contracts fp32->bf16 (4 rows each) + row norms
//  blocks 2048..4095: laws fp32->bf16 (2048 elems each)
//  blocks 4096..4351: Gram G[n] = laws[n]@laws[n]^T via MFMA, reading fp32
//                     laws directly with inline bf16 conversion (no dep on
//                     the prep blocks). 256 blocks = (n, 32-row stripe).
// ---------------------------------------------------------------------------
__global__ __launch_bounds__(256) void prep_gram_kernel(
    const float* __restrict__ con, const float* __restrict__ laws,
    unsigned short* __restrict__ lawsB, unsigned short* __restrict__ conB,
    float* __restrict__ cnorm, unsigned short* __restrict__ G) {
  const int bid = blockIdx.x;
  const int t = threadIdx.x;
  if (bid < 2048) {
    const int r = bid * 4 + (t >> 6);
    const int lane = t & 63;
    const float4* src = (const float4*)(con + r * DN + lane * 8);
    float4 x0 = src[0], x1 = src[1];
    unsigned short h[8];
    h[0] = f2bf(x0.x); h[1] = f2bf(x0.y); h[2] = f2bf(x0.z); h[3] = f2bf(x0.w);
    h[4] = f2bf(x1.x); h[5] = f2bf(x1.y); h[6] = f2bf(x1.z); h[7] = f2bf(x1.w);
    *(v8s*)(conB + r * DN + lane * 8) = *(v8s*)h;
    float s = x0.x * x0.x + x0.y * x0.y + x0.z * x0.z + x0.w * x0.w +
              x1.x * x1.x + x1.y * x1.y + x1.z * x1.z + x1.w * x1.w;
#pragma unroll
    for (int m = 1; m < 64; m <<= 1) s += __shfl_xor(s, m, 64);
    if (lane == 0) cnorm[r] = sqrtf(s);
  } else if (bid < 4096) {
    const int off = (bid - 2048) * 2048 + t * 8;
    const float4* src = (const float4*)(laws + off);
    float4 x0 = src[0], x1 = src[1];
    unsigned short h[8];
    h[0] = f2bf(x0.x); h[1] = f2bf(x0.y); h[2] = f2bf(x0.z); h[3] = f2bf(x0.w);
    h[4] = f2bf(x1.x); h[5] = f2bf(x1.y); h[6] = f2bf(x1.z); h[7] = f2bf(x1.w);
    *(v8s*)(lawsB + off) = *(v8s*)h;
  } else {
    const int gb = bid - 4096;  // 0..255
    const int n = gb >> 3;
    const int m0 = (gb & 7) << 5;  // 32-row stripe
    const int lane = t & 63;
    const int w = t >> 6;  // 4 waves
    const int quad = lane >> 4;
    const int l16 = lane & 15;
    const int wc = w << 6;  // wave col offset (64 cols)
    const float* lawN = laws + n * (LN * DN);

    v4f acc[2][4];
#pragma unroll
    for (int a = 0; a < 2; ++a)
#pragma unroll
      for (int b = 0; b < 4; ++b) acc[a][b] = (v4f){0.f, 0.f, 0.f, 0.f};

    for (int ch = 0; ch < 16; ++ch) {
      const int dk = (ch << 5) + quad * 8;
      v8s af0 = ld8f(lawN + (m0 + l16) * DN + dk);
      v8s af1 = ld8f(lawN + (m0 + 16 + l16) * DN + dk);
#pragma unroll
      for (int rt = 0; rt < 4; ++rt) {
        v8s bf = ld8f(lawN + (wc + rt * 16 + l16) * DN + dk);
        acc[0][rt] = __builtin_amdgcn_mfma_f32_16x16x32_bf16(af0, bf, acc[0][rt], 0, 0, 0);
        acc[1][rt] = __builtin_amdgcn_mfma_f32_16x16x32_bf16(af1, bf, acc[1][rt], 0, 0, 0);
      }
    }
    unsigned short* g = G + n * (LN * LN);
#pragma unroll
    for (int tl = 0; tl < 2; ++tl)
#pragma unroll
      for (int reg = 0; reg < 4; ++reg) {
        const int l = m0 + tl * 16 + quad * 4 + reg;
#pragma unroll
        for (int rt = 0; rt < 4; ++rt)
          g[l * LN + wc + rt * 16 + l16] = f2bf(acc[tl][rt][reg]);
      }
  }
}

// ---------------------------------------------------------------------------
// Main: one block per (n,c), 512 threads (8 waves). Software-pipelined
// staging: per chunk, ONE barrier (= consumer drain of last iteration's
// prefetch), then prefetch next chunk, then compute current chunk — the
// prefetch overlaps the whole compute phase.
// Phase A: S = laws[n]@con[c]^T; B-op (con) staged via global_load_lds dbuf,
//          A-frags direct global (2/wave/chunk, issued before prefetch so the
//          auto-waitcnt is vmcnt(2)); softmax rows in-reg -> sAt; w12 in regs.
// Phase B: U = At@G, G staged dbuf; nsq[r] = sum_l At[r,l]U[r,l].
// Phase C: sim = sqrt(D)*w12/(w1*w2); out[c,n] = LSE_6 over r.
// ---------------------------------------------------------------------------
__global__ __launch_bounds__(512, 2) void main_kernel(
    const int* __restrict__ law_lens, const unsigned short* __restrict__ lawsB,
    const unsigned short* __restrict__ conB, const unsigned short* __restrict__ Gm,
    const float* __restrict__ cnorm, float* __restrict__ out) {
  extern __shared__ char smem[];
  unsigned short* sAt = (unsigned short*)smem;  // [256][256] swizzled
  char* stage = smem + STAGE_OFF;               // 2 x 16K buffers

  const int bid = blockIdx.x;
  const int n = bid >> 5;  // 32 consecutive blocks share one n
  const int c = bid & 31;
  const int t = threadIdx.x;
  const int lane = t & 63;
  const int w = t >> 6;  // wave 0..7
  const int quad = lane >> 4;
  const int l16 = lane & 15;
  const int sub = t & 3;                   // staging: which 16B of a 64B row
  const int rQ = t >> 2;                   // staging: row within 128-row group
  const int subx = sub ^ ((rQ >> 1) & 3);  // swizzled source chunk
  const int len = law_lens[n];

  const unsigned short* lawN = lawsB + n * (LN * DN);
  const unsigned short* conC = conB + c * (RN * DN);
  const unsigned short* Gn = Gm + n * (LN * LN);

  float w12p[16];
#pragma unroll
  for (int i = 0; i < 16; ++i) w12p[i] = 0.f;

  // ---------------- Phase A ----------------
  {
    const unsigned short* a0p = lawN + (w * 32 + l16) * DN + quad * 8;
    const unsigned short* a1p = a0p + 16 * DN;

    v4f acc[2][16];
#pragma unroll
    for (int a = 0; a < 2; ++a)
#pragma unroll
      for (int b = 0; b < 16; ++b) acc[a][b] = (v4f){0.f, 0.f, 0.f, 0.f};

    // Prologue: stage chunk 0 into buf0.
#pragma unroll
    for (int i = 0; i < 2; ++i)
      gl2lds16(conC + (i * 128 + rQ) * DN + subx * 8,
               stage + i * 8192 + t * 16);

    for (int ch = 0; ch < 16; ++ch) {
      const int dk = ch << 5;
      __syncthreads();  // drains chunk-ch staging (in flight since iter ch-1)
      // A-frags FIRST (older than prefetch -> auto-wait becomes vmcnt(2)).
      v8s af0 = *(const v8s*)(a0p + dk);
      v8s af1 = *(const v8s*)(a1p + dk);
      __builtin_amdgcn_sched_barrier(0);
      if (ch < 15) {  // prefetch chunk ch+1 into the other buffer
        char* dst = stage + ((ch + 1) & 1) * 16384;
#pragma unroll
        for (int i = 0; i < 2; ++i)
          gl2lds16(conC + (i * 128 + rQ) * DN + (dk + 32) + subx * 8,
                   dst + i * 8192 + t * 16);
      }
      __builtin_amdgcn_sched_barrier(0);
      const unsigned short* cs =
          (const unsigned short*)(stage + (ch & 1) * 16384);
#pragma unroll
      for (int rt = 0; rt < 16; ++rt) {
        v8s bf = *stgFrag(cs, rt * 16 + l16, quad);
        acc[0][rt] = __builtin_amdgcn_mfma_f32_16x16x32_bf16(af0, bf, acc[0][rt], 0, 0, 0);
        acc[1][rt] = __builtin_amdgcn_mfma_f32_16x16x32_bf16(af1, bf, acc[1][rt], 0, 0, 0);
      }
    }
    // Row ops: row l lives in 16 lanes (C layout col=lane&15 -> r index).
    // 4 regs of a tile = 4 consecutive sAt columns -> packed b64 writes.
#pragma unroll
    for (int tl = 0; tl < 2; ++tl) {
      unsigned int pk[16][2];
#pragma unroll
      for (int reg = 0; reg < 4; ++reg) {
        const int lg = w * 32 + tl * 16 + quad * 4 + reg;
        float v[16], lv[16];
        float ss = 0.f, mx = -1e30f;
#pragma unroll
        for (int rt = 0; rt < 16; ++rt) {
          v[rt] = acc[tl][rt][reg] * 0.04419417382415922f;  // 1/sqrt(512)
          lv[rt] = v[rt] > 0.f ? v[rt] : 0.1f * v[rt];
          ss += lv[rt] * lv[rt];
          mx = fmaxf(mx, lv[rt]);
        }
#pragma unroll
        for (int m = 1; m < 16; m <<= 1) {
          ss += __shfl_xor(ss, m, 64);
          mx = fmaxf(mx, __shfl_xor(mx, m, 64));
        }
        const float inv = 1.f / (sqrtf(ss) + 1e-8f);
        const float xm = mx * inv;
        float e[16];
        float den = 0.f;
#pragma unroll
        for (int rt = 0; rt < 16; ++rt) {
          e[rt] = __expf(lv[rt] * inv - xm);
          den += e[rt];
        }
#pragma unroll
        for (int m = 1; m < 16; m <<= 1) den += __shfl_xor(den, m, 64);
        const float sc = (lg < len) ? 4.f / den : 0.f;  // SMOOTH/denom, masked
#pragma unroll
        for (int rt = 0; rt < 16; ++rt) {
          const float a = e[rt] * sc;
          w12p[rt] += a * v[rt];  // raw S -> cosine numerator
          const unsigned int h = f2bf(a);
          if (reg & 1)
            pk[rt][reg >> 1] |= h << 16;
          else
            pk[rt][reg >> 1] = h;
        }
      }
      const int lg0 = w * 32 + tl * 16 + quad * 4;
#pragma unroll
      for (int rt = 0; rt < 16; ++rt)
        *(uint2*)(sAt + satIdx(rt * 16 + l16, lg0)) = *(uint2*)pk[rt];
    }
  }

  __syncthreads();  // sAt writes done (all waves); conS reads done

  // Prologue: stage Gs chunk 0 into buf0 (overlaps w12 shuffles below).
#pragma unroll
  for (int i = 0; i < 2; ++i)
    gl2lds16(Gn + (i * 128 + rQ) * LN + subx * 8, stage + i * 8192 + t * 16);

  // Reduce w12 partials across quads; keep in registers through phase B.
#pragma unroll
  for (int rt = 0; rt < 16; ++rt) {
    w12p[rt] += __shfl_xor(w12p[rt], 16, 64);
    w12p[rt] += __shfl_xor(w12p[rt], 32, 64);
  }

  // ---------------- Phase B ----------------
  float nsv[2][4];
  {
    v4f acc[2][16];
#pragma unroll
    for (int a = 0; a < 2; ++a)
#pragma unroll
      for (int b = 0; b < 16; ++b) acc[a][b] = (v4f){0.f, 0.f, 0.f, 0.f};

    for (int ch = 0; ch < 8; ++ch) {
      const int lk = ch << 5;
      __syncthreads();  // drains chunk-ch Gs staging
      v8s af0 = *(const v8s*)(sAt + satIdx(w * 32 + l16, lk + quad * 8));
      v8s af1 = *(const v8s*)(sAt + satIdx(w * 32 + 16 + l16, lk + quad * 8));
      __builtin_amdgcn_sched_barrier(0);
      if (ch < 7) {  // prefetch chunk ch+1
        char* dst = stage + ((ch + 1) & 1) * 16384;
#pragma unroll
        for (int i = 0; i < 2; ++i)
          gl2lds16(Gn + (i * 128 + rQ) * LN + (lk + 32) + subx * 8,
                   dst + i * 8192 + t * 16);
      }
      __builtin_amdgcn_sched_barrier(0);
      const unsigned short* gs =
          (const unsigned short*)(stage + (ch & 1) * 16384);
#pragma unroll
      for (int lt = 0; lt < 16; ++lt) {
        v8s bf = *stgFrag(gs, lt * 16 + l16, quad);  // G row (symmetric)
        acc[0][lt] = __builtin_amdgcn_mfma_f32_16x16x32_bf16(af0, bf, acc[0][lt], 0, 0, 0);
        acc[1][lt] = __builtin_amdgcn_mfma_f32_16x16x32_bf16(af1, bf, acc[1][lt], 0, 0, 0);
      }
    }
    // nsq[r] = sum_l At[r,l] * U[r,l] (reads sAt + registers only)
#pragma unroll
    for (int tl = 0; tl < 2; ++tl) {
#pragma unroll
      for (int reg = 0; reg < 4; ++reg) {
        const int r = w * 32 + tl * 16 + quad * 4 + reg;
        float s = 0.f;
#pragma unroll
        for (int lt = 0; lt < 16; ++lt)
          s += acc[tl][lt][reg] * bf2f(sAt[satIdx(r, lt * 16 + l16)]);
#pragma unroll
        for (int m = 1; m < 16; m <<= 1) s += __shfl_xor(s, m, 64);
        nsv[tl][reg] = s;
      }
    }
  }

  // ---------------- Phase C (reductions overlay the stage region) ----------
  float* w12s = (float*)stage;           // [8][256] = 8K
  float* nsqS = (float*)(stage + 8192);  // [256]    = 1K
  float* red = (float*)(stage + 9216);   // [8]
  __syncthreads();  // all Gs reads done; stage is free for reductions
  if (l16 == 0) {
#pragma unroll
    for (int tl = 0; tl < 2; ++tl)
#pragma unroll
      for (int reg = 0; reg < 4; ++reg)
        nsqS[w * 32 + tl * 16 + quad * 4 + reg] = nsv[tl][reg];
  }
  if (lane < 16) {
#pragma unroll
    for (int rt = 0; rt < 16; ++rt) w12s[w * 256 + rt * 16 + lane] = w12p[rt];
  }
  __syncthreads();
  float p = 0.f;
  if (t < 256) {
    float w12 = 0.f;
#pragma unroll
    for (int i = 0; i < 8; ++i) w12 += w12s[i * 256 + t];
    const float w1 = cnorm[c * RN + t];
    const float w2 = sqrtf(fmaxf(nsqS[t], 0.f));
    const float sim = (w12 * 22.627416997969522f) / fmaxf(w1 * w2, 1e-8f);
    p = __expf(6.f * sim);
  }
#pragma unroll
  for (int m = 1; m < 64; m <<= 1) p += __shfl_xor(p, m, 64);
  if (lane == 0) red[w] = p;
  __syncthreads();
  if (t == 0) {
    float s = 0.f;
#pragma unroll
    for (int i = 0; i < 8; ++i) s += red[i];
    out[c * NN + n] = logf(s) / 6.f;
  }
}

// ---------------------------------------------------------------------------
extern "C" void kernel_launch(void* const* d_in, const int* in_sizes, int n_in,
                              void* d_out, int out_size, void* d_ws, size_t ws_size,
                              hipStream_t stream) {
  (void)in_sizes; (void)n_in; (void)out_size;
  const float* contracts = (const float*)d_in[0];
  const float* laws = (const float*)d_in[1];
  const int* law_lens = (const int*)d_in[2];
  float* out = (float*)d_out;

  // Workspace layout (21,004,288 B total)
  unsigned short* lawsB = (unsigned short*)d_ws;  // 8 MiB
  unsigned short* conB = lawsB + NN * LN * DN;    // 8 MiB
  unsigned short* G = conB + CN * RN * DN;        // 4 MiB
  float* cnorm = (float*)(G + NN * LN * LN);      // 32 KiB
  if (ws_size < (size_t)21004288) return;

  hipFuncSetAttribute((const void*)main_kernel,
                      hipFuncAttributeMaxDynamicSharedMemorySize, SMEM_TOTAL);

  // 2048 contract-prep + 2048 laws-prep + 256 gram blocks, one launch.
  prep_gram_kernel<<<4352, 256, 0, stream>>>(contracts, laws, lawsB, conB,
                                             cnorm, G);
  main_kernel<<<1024, 512, SMEM_TOTAL, stream>>>(law_lens, lawsB, conB, G,
                                                 cnorm, out);
}

// Round 7
// 249.577 us; speedup vs baseline: 2.0665x; 1.2917x over previous
//
#include <hip/hip_runtime.h>
#include <hip/hip_bf16.h>

// Sizes fixed by the reference problem.
#define CN 32
#define RN 256
#define DN 512
#define NN 32
#define LN 256

// LDS layout of main kernel (bytes):
//  sAt   : bf16 [256][256] = 131072, 16B-chunk XOR swizzle (chunk ^= r&7)
//  stage : 32768 = double-buffered staging (conS / Gs), 16K per buffer.
//          Epilogue reductions (w12s 16K, nsqS 1K, red) overlay this region.
//  total : 163840 = exactly 160 KiB (1 block/CU, 16 waves, 4 waves/SIMD)
#define STAGE_OFF 131072
#define SMEM_TOTAL 163840

typedef short v8s __attribute__((ext_vector_type(8)));
typedef float v4f __attribute__((ext_vector_type(4)));
typedef const __attribute__((address_space(1))) void* gas1_t;
typedef __attribute__((address_space(3))) void* las3_t;

__device__ __forceinline__ void gl2lds16(const void* g, void* l) {
  __builtin_amdgcn_global_load_lds((gas1_t)g, (las3_t)l, 16, 0, 0);
}

__device__ __forceinline__ unsigned short f2bf(float x) {
  unsigned int u = __float_as_uint(x);
  u = (u + 0x7fffu + ((u >> 16) & 1u)) >> 16;  // RNE
  return (unsigned short)u;
}
__device__ __forceinline__ float bf2f(unsigned short h) {
  return __uint_as_float(((unsigned int)h) << 16);
}

// Staging buffers ([256][32] shorts): 16B chunks XOR-swizzled with (r>>1)&3.
// Writes absorb the swizzle in the global fetch column; reads via this helper.
__device__ __forceinline__ const v8s* stgFrag(const unsigned short* buf, int r,
                                              int quad) {
  return (const v8s*)(buf + r * 32 + ((quad ^ ((r >> 1) & 3)) << 3));
}

// sAt addressing: row-major stride 256 shorts, 16B chunks XOR-swizzled by row.
__device__ __forceinline__ int satIdx(int r, int col) {
  return (r << 8) | ((((col >> 3) ^ (r & 7)) << 3) | (col & 7));
}

// ---------------------------------------------------------------------------
// Prep: fp32 -> bf16 copies of laws & contracts, plus ||contracts[c,r,:]||.
// blocks 0..2047: contracts (4 rows each, + row norms);
// blocks 2048..4095: laws (2048 elements each).
// ---------------------------------------------------------------------------
__global__ __launch_bounds__(256) void prep_kernel(
    const float* __restrict__ con, const float* __restrict__ laws,
    unsigned short* __restrict__ lawsB, unsigned short* __restrict__ conB,
    float* __restrict__ cnorm) {
  const int bid = blockIdx.x;
  const int t = threadIdx.x;
  if (bid < 2048) {
    const int r = bid * 4 + (t >> 6);
    const int lane = t & 63;
    const float4* src = (const float4*)(con + r * DN + lane * 8);
    float4 x0 = src[0], x1 = src[1];
    unsigned short h[8];
    h[0] = f2bf(x0.x); h[1] = f2bf(x0.y); h[2] = f2bf(x0.z); h[3] = f2bf(x0.w);
    h[4] = f2bf(x1.x); h[5] = f2bf(x1.y); h[6] = f2bf(x1.z); h[7] = f2bf(x1.w);
    *(v8s*)(conB + r * DN + lane * 8) = *(v8s*)h;
    float s = x0.x * x0.x + x0.y * x0.y + x0.z * x0.z + x0.w * x0.w +
              x1.x * x1.x + x1.y * x1.y + x1.z * x1.z + x1.w * x1.w;
#pragma unroll
    for (int m = 1; m < 64; m <<= 1) s += __shfl_xor(s, m, 64);
    if (lane == 0) cnorm[r] = sqrtf(s);
  } else {
    const int off = (bid - 2048) * 2048 + t * 8;
    const float4* src = (const float4*)(laws + off);
    float4 x0 = src[0], x1 = src[1];
    unsigned short h[8];
    h[0] = f2bf(x0.x); h[1] = f2bf(x0.y); h[2] = f2bf(x0.z); h[3] = f2bf(x0.w);
    h[4] = f2bf(x1.x); h[5] = f2bf(x1.y); h[6] = f2bf(x1.z); h[7] = f2bf(x1.w);
    *(v8s*)(lawsB + off) = *(v8s*)h;
  }
}

// ---------------------------------------------------------------------------
// Gram via MFMA (R3 structure: gl2lds staging, verified fast).
// 128 blocks = (n, 64-row quarter). 8 waves; wave tile 32 rows x 64 cols.
// ---------------------------------------------------------------------------
__global__ __launch_bounds__(512) void gramm_kernel(
    const unsigned short* __restrict__ lawsB, unsigned short* __restrict__ G) {
  __shared__ unsigned short lawsAll[256 * 32];  // 16 KB (B operand: all rows)
  __shared__ unsigned short lawsSub[64 * 32];   // 4 KB  (A operand: 64 rows)
  const int bx = blockIdx.x;
  const int n = bx >> 2;
  const int m0 = (bx & 3) << 6;
  const int t = threadIdx.x;
  const int lane = t & 63;
  const int w = t >> 6;
  const int quad = lane >> 4;
  const int l16 = lane & 15;
  const int sub = t & 3;
  const int rQ = t >> 2;
  const int subx = sub ^ ((rQ >> 1) & 3);
  const unsigned short* lawN = lawsB + n * (LN * DN);
  const int wr = (w & 1) << 5;
  const int wc = (w >> 1) << 6;

  v4f acc[2][4];
#pragma unroll
  for (int a = 0; a < 2; ++a)
#pragma unroll
    for (int b = 0; b < 4; ++b) acc[a][b] = (v4f){0.f, 0.f, 0.f, 0.f};

  for (int ch = 0; ch < 16; ++ch) {
    const int dk = ch << 5;
    __syncthreads();
#pragma unroll
    for (int i = 0; i < 2; ++i)
      gl2lds16(lawN + (i * 128 + rQ) * DN + dk + subx * 8,
               (char*)lawsAll + i * 8192 + t * 16);
    if (t < 256)
      gl2lds16(lawN + (m0 + rQ) * DN + dk + subx * 8, (char*)lawsSub + t * 16);
    __syncthreads();
    v8s af0 = *stgFrag(lawsSub, wr + l16, quad);
    v8s af1 = *stgFrag(lawsSub, wr + 16 + l16, quad);
#pragma unroll
    for (int rt = 0; rt < 4; ++rt) {
      v8s bf = *stgFrag(lawsAll, wc + rt * 16 + l16, quad);
      acc[0][rt] = __builtin_amdgcn_mfma_f32_16x16x32_bf16(af0, bf, acc[0][rt], 0, 0, 0);
      acc[1][rt] = __builtin_amdgcn_mfma_f32_16x16x32_bf16(af1, bf, acc[1][rt], 0, 0, 0);
    }
  }
  unsigned short* g = G + n * (LN * LN);
#pragma unroll
  for (int tl = 0; tl < 2; ++tl)
#pragma unroll
    for (int reg = 0; reg < 4; ++reg) {
      const int l = m0 + wr + tl * 16 + quad * 4 + reg;
#pragma unroll
      for (int rt = 0; rt < 4; ++rt)
        g[l * LN + wc + rt * 16 + l16] = f2bf(acc[tl][rt][reg]);
    }
}

// ---------------------------------------------------------------------------
// Main: one block per (n,c), 1024 threads = 16 waves (4 waves/SIMD for real
// latency hiding). Per-wave footprint halved vs the 512-thread version:
// acc[16] = 64 AGPRs; softmax uses streaming recompute (no v/lv/e arrays) so
// combined VGPR+AGPR fits the 128/wave budget of 4 waves/SIMD.
// Phase A: S = laws[n]@con[c]^T; con staged (gl2lds dbuf, 1 barrier/chunk),
//          A-frags direct global (1/wave/chunk, L1-resident); softmax rows
//          in-reg -> sAt bf16; w12 partials in registers.
// Phase B: U = At@G, G staged dbuf; nsq[r] = sum_l At[r,l]U[r,l].
// Phase C: sim = sqrt(D)*w12/(w1*w2); out[c,n] = LSE_6 over r.
// ---------------------------------------------------------------------------
__global__ __launch_bounds__(1024, 4) void main_kernel(
    const int* __restrict__ law_lens, const unsigned short* __restrict__ lawsB,
    const unsigned short* __restrict__ conB, const unsigned short* __restrict__ Gm,
    const float* __restrict__ cnorm, float* __restrict__ out) {
  extern __shared__ char smem[];
  unsigned short* sAt = (unsigned short*)smem;  // [256][256] swizzled
  char* stage = smem + STAGE_OFF;               // 2 x 16K buffers

  const int bid = blockIdx.x;
  const int n = bid >> 5;  // 32 consecutive blocks share one n
  const int c = bid & 31;
  const int t = threadIdx.x;
  const int lane = t & 63;
  const int w = t >> 6;  // wave 0..15
  const int quad = lane >> 4;
  const int l16 = lane & 15;
  const int sub = t & 3;                   // staging: which 16B of a 64B row
  const int rQ = t >> 2;                   // staging: row 0..255
  const int subx = sub ^ ((rQ >> 1) & 3);  // swizzled source chunk
  const int len = law_lens[n];

  const unsigned short* lawN = lawsB + n * (LN * DN);
  const unsigned short* conC = conB + c * (RN * DN);
  const unsigned short* Gn = Gm + n * (LN * LN);

  float w12p[16];
#pragma unroll
  for (int i = 0; i < 16; ++i) w12p[i] = 0.f;

  // ---------------- Phase A ----------------
  {
    const unsigned short* a0p = lawN + (w * 16 + l16) * DN + quad * 8;

    v4f acc[16];
#pragma unroll
    for (int b = 0; b < 16; ++b) acc[b] = (v4f){0.f, 0.f, 0.f, 0.f};

    // Prologue: stage chunk 0 into buf0 (one gl2lds per thread = 16KB).
    gl2lds16(conC + rQ * DN + subx * 8, stage + t * 16);

    for (int ch = 0; ch < 16; ++ch) {
      const int dk = ch << 5;
      __syncthreads();  // drains chunk-ch staging (in flight since iter ch-1)
      v8s af = *(const v8s*)(a0p + dk);  // direct global A-frag (L1-hot)
      __builtin_amdgcn_sched_barrier(0);
      if (ch < 15)  // prefetch chunk ch+1 into the other buffer
        gl2lds16(conC + rQ * DN + (dk + 32) + subx * 8,
                 stage + ((ch + 1) & 1) * 16384 + t * 16);
      __builtin_amdgcn_sched_barrier(0);
      const unsigned short* cs =
          (const unsigned short*)(stage + (ch & 1) * 16384);
#pragma unroll
      for (int rt = 0; rt < 16; ++rt) {
        v8s bf = *stgFrag(cs, rt * 16 + l16, quad);
        acc[rt] = __builtin_amdgcn_mfma_f32_16x16x32_bf16(af, bf, acc[rt], 0, 0, 0);
      }
    }
    // Softmax row ops, streaming (recompute lv/exp; no per-row arrays).
    // Row l = w*16 + quad*4 + reg lives in 16 lanes (col=lane&15 -> r tile).
    // |lv·inv| <= 1 (l2-normalized), so exp needs no max subtraction.
#pragma unroll
    for (int reg = 0; reg < 4; ++reg) {
      const int lg = w * 16 + quad * 4 + reg;
      float ss = 0.f;
#pragma unroll
      for (int rt = 0; rt < 16; ++rt) {
        const float v = acc[rt][reg] * 0.04419417382415922f;  // 1/sqrt(512)
        const float lv = v > 0.f ? v : 0.1f * v;
        ss += lv * lv;
      }
#pragma unroll
      for (int m = 1; m < 16; m <<= 1) ss += __shfl_xor(ss, m, 64);
      const float inv = 1.f / (sqrtf(ss) + 1e-8f);
      float den = 0.f;
#pragma unroll
      for (int rt = 0; rt < 16; ++rt) {
        const float v = acc[rt][reg] * 0.04419417382415922f;
        const float lv = v > 0.f ? v : 0.1f * v;
        den += __expf(lv * inv);
      }
#pragma unroll
      for (int m = 1; m < 16; m <<= 1) den += __shfl_xor(den, m, 64);
      const float sc = (lg < len) ? 4.f / den : 0.f;  // SMOOTH/denom, masked
#pragma unroll
      for (int rt = 0; rt < 16; ++rt) {
        const float v = acc[rt][reg] * 0.04419417382415922f;
        const float lv = v > 0.f ? v : 0.1f * v;
        const float a = __expf(lv * inv) * sc;
        w12p[rt] += a * v;  // raw S -> cosine numerator
        sAt[satIdx(rt * 16 + l16, lg)] = f2bf(a);
      }
    }
  }

  __syncthreads();  // sAt writes done (all waves); conS reads done

  // Prologue: stage Gs chunk 0 into buf0 (overlaps w12 shuffles below).
  gl2lds16(Gn + rQ * LN + subx * 8, stage + t * 16);

  // Reduce w12 partials across quads; keep in registers through phase B.
#pragma unroll
  for (int rt = 0; rt < 16; ++rt) {
    w12p[rt] += __shfl_xor(w12p[rt], 16, 64);
    w12p[rt] += __shfl_xor(w12p[rt], 32, 64);
  }

  // ---------------- Phase B ----------------
  float nsv[4];
  {
    v4f acc[16];
#pragma unroll
    for (int b = 0; b < 16; ++b) acc[b] = (v4f){0.f, 0.f, 0.f, 0.f};

    for (int ch = 0; ch < 8; ++ch) {
      const int lk = ch << 5;
      __syncthreads();  // drains chunk-ch Gs staging
      v8s af = *(const v8s*)(sAt + satIdx(w * 16 + l16, lk + quad * 8));
      __builtin_amdgcn_sched_barrier(0);
      if (ch < 7)  // prefetch chunk ch+1
        gl2lds16(Gn + rQ * LN + (lk + 32) + subx * 8,
                 stage + ((ch + 1) & 1) * 16384 + t * 16);
      __builtin_amdgcn_sched_barrier(0);
      const unsigned short* gs =
          (const unsigned short*)(stage + (ch & 1) * 16384);
#pragma unroll
      for (int lt = 0; lt < 16; ++lt) {
        v8s bf = *stgFrag(gs, lt * 16 + l16, quad);  // G row (symmetric)
        acc[lt] = __builtin_amdgcn_mfma_f32_16x16x32_bf16(af, bf, acc[lt], 0, 0, 0);
      }
    }
    // nsq[r] = sum_l At[r,l] * U[r,l] (reads sAt + registers only)
#pragma unroll
    for (int reg = 0; reg < 4; ++reg) {
      const int r = w * 16 + quad * 4 + reg;
      float s = 0.f;
#pragma unroll
      for (int lt = 0; lt < 16; ++lt)
        s += acc[lt][reg] * bf2f(sAt[satIdx(r, lt * 16 + l16)]);
#pragma unroll
      for (int m = 1; m < 16; m <<= 1) s += __shfl_xor(s, m, 64);
      nsv[reg] = s;
    }
  }

  // ---------------- Phase C (reductions overlay the stage region) ----------
  float* w12s = (float*)stage;            // [16][256] = 16K
  float* nsqS = (float*)(stage + 16384);  // [256] = 1K
  float* red = (float*)(stage + 17408);   // [4]
  __syncthreads();  // all Gs reads done; stage is free for reductions
  if (l16 == 0) {
#pragma unroll
    for (int reg = 0; reg < 4; ++reg)
      nsqS[w * 16 + quad * 4 + reg] = nsv[reg];
  }
  if (lane < 16) {
#pragma unroll
    for (int rt = 0; rt < 16; ++rt) w12s[w * 256 + rt * 16 + lane] = w12p[rt];
  }
  __syncthreads();
  float p = 0.f;
  if (t < 256) {
    float w12 = 0.f;
#pragma unroll
    for (int i = 0; i < 16; ++i) w12 += w12s[i * 256 + t];
    const float w1 = cnorm[c * RN + t];
    const float w2 = sqrtf(fmaxf(nsqS[t], 0.f));
    const float sim = (w12 * 22.627416997969522f) / fmaxf(w1 * w2, 1e-8f);
    p = __expf(6.f * sim);
  }
#pragma unroll
  for (int m = 1; m < 64; m <<= 1) p += __shfl_xor(p, m, 64);
  if (t < 256 && lane == 0) red[w] = p;
  __syncthreads();
  if (t == 0) {
    out[c * NN + n] = logf(red[0] + red[1] + red[2] + red[3]) / 6.f;
  }
}

// ---------------------------------------------------------------------------
extern "C" void kernel_launch(void* const* d_in, const int* in_sizes, int n_in,
                              void* d_out, int out_size, void* d_ws, size_t ws_size,
                              hipStream_t stream) {
  (void)in_sizes; (void)n_in; (void)out_size;
  const float* contracts = (const float*)d_in[0];
  const float* laws = (const float*)d_in[1];
  const int* law_lens = (const int*)d_in[2];
  float* out = (float*)d_out;

  // Workspace layout (21,004,288 B total)
  unsigned short* lawsB = (unsigned short*)d_ws;  // 8 MiB
  unsigned short* conB = lawsB + NN * LN * DN;    // 8 MiB
  unsigned short* G = conB + CN * RN * DN;        // 4 MiB
  float* cnorm = (float*)(G + NN * LN * LN);      // 32 KiB
  if (ws_size < (size_t)21004288) return;

  hipFuncSetAttribute((const void*)main_kernel,
                      hipFuncAttributeMaxDynamicSharedMemorySize, SMEM_TOTAL);

  prep_kernel<<<4096, 256, 0, stream>>>(contracts, laws, lawsB, conB, cnorm);
  gramm_kernel<<<128, 512, 0, stream>>>(lawsB, G);
  main_kernel<<<1024, 1024, SMEM_TOTAL, stream>>>(law_lens, lawsB, conB, G,
                                                  cnorm, out);
}